// Round 2
// baseline (1418.111 us; speedup 1.0000x reference)
//
#include <hip/hip_runtime.h>
#include <hip/hip_fp16.h>

// GPTQ int4 dequant + GEMM, fused.
//   x        [4,2048,4096] fp32  -> A [M=8192][K=4096], cast to fp16 (RTE, matches ref)
//   qweight  [512,11008] int32   -> W[k][n]: nibble j of qweight[k/8][n], k = 8*(k/8)+j
//   qzeros   [32,1376]  int32    -> z[g][n]: nibble (n%8) of qzeros[g][n/8]
//   scales   [32,11008] -- fp16 in the reference, but the harness materializes
//            non-bf16 float inputs as FLOAT32 buffers. Read as float. (R1's 8e5
//            absmax came from reading this buffer at half-granularity.)
//   dequant  fp16( (w - z[g]) * s[g] ),  g = k/128   (fp32 math, RTE cast == ref)
//   out      [M][N=11008] fp32, fp32 accumulation via MFMA
//
// Structure: 128x128 tile, BK=64, 4 waves in 2x2, wave tile 64x64 = 4x4 frags of
// mfma_f32_16x16x32_f16. LDS As[m][k], Bs[n][k], k-contiguous, LDK=72 halves
// (144 B row stride = 36 banks -> 2-way aliasing only, free per m136).

#define M_TOT 8192
#define N_TOT 11008
#define K_TOT 4096

#define BM 128
#define BN 128
#define BK 64
#define LDK 72  // padded K stride in halves (+8 -> 16B pad)

typedef _Float16 half8 __attribute__((ext_vector_type(8)));
typedef _Float16 half4v __attribute__((ext_vector_type(4)));
typedef float float4v __attribute__((ext_vector_type(4)));

__global__ __launch_bounds__(256) void gptq_fused_gemm(
    const float* __restrict__ x,
    const int* __restrict__ qw,
    const unsigned* __restrict__ qz,
    const float* __restrict__ sc,   // fp32 buffer (harness upcasts fp16 inputs)
    float* __restrict__ out)
{
    __shared__ _Float16 As[BM * LDK];
    __shared__ _Float16 Bs[BN * LDK];

    const int tid = threadIdx.x;
    const int bn = blockIdx.x;            // 0..85  (N/128)
    const int bm = blockIdx.y;            // 0..63  (M/128)
    const int m0 = bm * BM;
    const int n0 = bn * BN;

    const int wave = tid >> 6;
    const int lane = tid & 63;
    const int wr = wave >> 1;             // wave row (m), 0..1
    const int wc = wave & 1;              // wave col (n), 0..1
    const int l16 = lane & 15;
    const int quad = lane >> 4;

    // A staging: thread -> (row a_m + 16*i, float4 a_kq); lanes 0..15 contiguous in k
    const int a_kq = tid & 15;            // float4 index along k (k = 4*a_kq)
    const int a_m  = tid >> 4;            // 0..15, covers rows a_m + 16*i
    // B staging: thread -> column b_n, qweight rows b_rr + 2*i
    const int b_n  = tid & 127;
    const int b_rr = tid >> 7;
    const int ncol = n0 + b_n;

    float4v acc[4][4] = {};

    for (int k0 = 0; k0 < K_TOT; k0 += BK) {
        __syncthreads();  // protect LDS from previous iteration's reads

        // ---- stage A: x[m0..+128][k0..+64] fp32 -> As[m][k] fp16 (RTE)
        {
            const float* src = x + (size_t)(m0 + a_m) * K_TOT + k0 + a_kq * 4;
            #pragma unroll
            for (int i = 0; i < 8; ++i) {
                float4v v = *(const float4v*)(src + (size_t)i * 16 * K_TOT);
                half4v h;
                h[0] = (_Float16)v[0];
                h[1] = (_Float16)v[1];
                h[2] = (_Float16)v[2];
                h[3] = (_Float16)v[3];
                *(half4v*)&As[(a_m + 16 * i) * LDK + a_kq * 4] = h;
            }
        }

        // ---- stage B: dequant qweight[k0/8 .. +8][n0..+128] -> Bs[n][k] fp16
        {
            const int g = k0 >> 7;  // group = k0/128; BK=64 divides group size
            const float s_f = sc[g * N_TOT + ncol];
            const unsigned zraw = qz[g * (N_TOT / 8) + (ncol >> 3)];
            const float z_f = (float)((zraw >> ((ncol & 7) * 4)) & 15u);
            const int krow0 = k0 >> 3;
            #pragma unroll
            for (int i = 0; i < 4; ++i) {
                const int rr = b_rr + 2 * i;  // 0..7
                const unsigned raw = (unsigned)qw[(size_t)(krow0 + rr) * N_TOT + ncol];
                half8 w;
                #pragma unroll
                for (int j = 0; j < 8; ++j) {
                    float wf = (float)((raw >> (4 * j)) & 15u);
                    w[j] = (_Float16)((wf - z_f) * s_f);  // fp32 math, RTE cast == ref
                }
                *(half8*)&Bs[b_n * LDK + rr * 8] = w;  // ds_write_b128, 16B aligned
            }
        }

        __syncthreads();

        // ---- compute: 2 x (4 A-frags + 4 B-frags + 16 MFMA)
        #pragma unroll
        for (int kk = 0; kk < 2; ++kk) {
            half8 af[4], bf[4];
            #pragma unroll
            for (int i = 0; i < 4; ++i)  // A[m=l16][k=quad*8+j]
                af[i] = *(const half8*)&As[(wr * 64 + i * 16 + l16) * LDK + kk * 32 + quad * 8];
            #pragma unroll
            for (int j = 0; j < 4; ++j)  // B[k=quad*8+j][n=l16]
                bf[j] = *(const half8*)&Bs[(wc * 64 + j * 16 + l16) * LDK + kk * 32 + quad * 8];
            #pragma unroll
            for (int i = 0; i < 4; ++i)
                #pragma unroll
                for (int j = 0; j < 4; ++j)
                    acc[i][j] = __builtin_amdgcn_mfma_f32_16x16x32_f16(af[i], bf[j], acc[i][j], 0, 0, 0);
        }
    }

    // ---- epilogue: C/D layout col = lane&15 (n), row = quad*4 + reg (m)
    float* o = out + (size_t)(m0 + wr * 64) * N_TOT + (n0 + wc * 64);
    #pragma unroll
    for (int i = 0; i < 4; ++i)
        #pragma unroll
        for (int j = 0; j < 4; ++j)
            #pragma unroll
            for (int r = 0; r < 4; ++r)
                o[(size_t)(i * 16 + quad * 4 + r) * N_TOT + (j * 16 + l16)] = acc[i][j][r];
}

extern "C" void kernel_launch(void* const* d_in, const int* in_sizes, int n_in,
                              void* d_out, int out_size, void* d_ws, size_t ws_size,
                              hipStream_t stream) {
    const float* x = (const float*)d_in[0];
    const int* qw = (const int*)d_in[1];
    const unsigned* qz = (const unsigned*)d_in[2];
    const float* sc = (const float*)d_in[3];
    float* out = (float*)d_out;

    dim3 grid(N_TOT / BN, M_TOT / BM, 1);  // (86, 64)
    gptq_fused_gemm<<<grid, dim3(256, 1, 1), 0, stream>>>(x, qw, qz, sc, out);
}